// Round 8
// baseline (196.085 us; speedup 1.0000x reference)
//
#include <hip/hip_runtime.h>
#include <hip/hip_bf16.h>

#define B_ 4
#define L_ 1024
#define E_ 256
#define S_ 32
#define LOG2E 1.4426950408889634f

typedef __bf16 bf16x8 __attribute__((ext_vector_type(8)));
typedef float f32x4 __attribute__((ext_vector_type(4)));

__device__ __forceinline__ __bf16 bf_from_bits(unsigned short u) {
    __bf16 b;
    __builtin_memcpy(&b, &u, 2);
    return b;
}

__device__ __forceinline__ void split1(float x, unsigned short& h, unsigned short& l) {
    const unsigned u  = __float_as_uint(x);
    const unsigned hb = u & 0xFFFF0000u;
    h = (unsigned short)(hb >> 16);
    __bf16 lo = (__bf16)(x - __uint_as_float(hb));
    unsigned short lu;
    __builtin_memcpy(&lu, &lo, 2);
    l = lu;
}

// Path-B fallback only.
__device__ __forceinline__ void load8split(const float* __restrict__ p,
                                           bf16x8& h, bf16x8& l) {
    const float4 x0 = *(const float4*)p;
    const float4 x1 = *(const float4*)(p + 4);
    const float xs[8] = {x0.x, x0.y, x0.z, x0.w, x1.x, x1.y, x1.z, x1.w};
#pragma unroll
    for (int j = 0; j < 8; ++j) {
        const unsigned hb = __float_as_uint(xs[j]) & 0xFFFF0000u;
        h[j] = bf_from_bits((unsigned short)(__float_as_uint(xs[j]) >> 16));
        l[j] = (__bf16)(xs[j] - __uint_as_float(hb));
    }
}

// ===========================================================================
// Kernel 0: presplit (unchanged from R7).
// ===========================================================================
__global__ __launch_bounds__(256) void presplit(
    const float* __restrict__ A,
    const float* __restrict__ Wq, const float* __restrict__ Wk,
    const float* __restrict__ Wv,
    unsigned short* __restrict__ Ah, unsigned short* __restrict__ Al,
    unsigned short* __restrict__ Wh, unsigned short* __restrict__ Wl)
{
    const int e8 = (blockIdx.x * 256 + threadIdx.x) * 8;
    const float* src;
    unsigned short* dh;
    unsigned short* dl;
    if (e8 < 1048576) {
        src = A + e8; dh = Ah + e8; dl = Al + e8;
    } else {
        const int r = e8 - 1048576;
        const int m = r >> 16;          // 0=Wq 1=Wk 2=Wv
        const int o = r & 65535;
        src = (m == 0 ? Wq : m == 1 ? Wk : Wv) + o;
        dh = Wh + r; dl = Wl + r;
    }
    const float4 x0 = *(const float4*)src;
    const float4 x1 = *(const float4*)(src + 4);
    const float xs[8] = {x0.x, x0.y, x0.z, x0.w, x1.x, x1.y, x1.z, x1.w};
    unsigned short hs[8], ls[8];
#pragma unroll
    for (int j = 0; j < 8; ++j) split1(xs[j], hs[j], ls[j]);
    *(ushort4*)(dh)     = make_ushort4(hs[0], hs[1], hs[2], hs[3]);
    *(ushort4*)(dh + 4) = make_ushort4(hs[4], hs[5], hs[6], hs[7]);
    *(ushort4*)(dl)     = make_ushort4(ls[0], ls[1], ls[2], ls[3]);
    *(ushort4*)(dl + 4) = make_ushort4(ls[4], ls[5], ls[6], ls[7]);
}

// ===========================================================================
// Kernel 1: Q/K/V projection GEMM — R7's qkv_gemm4 with a `reps` outer loop
// (MEASUREMENT: reps=4, idempotent rewrites; divide dispatch dur by 4).
// ===========================================================================
__global__ __launch_bounds__(256) void qkv_gemm4(
    const unsigned short* __restrict__ Ah, const unsigned short* __restrict__ Al,
    const unsigned short* __restrict__ Wh, const unsigned short* __restrict__ Wl,
    const float* __restrict__ bq, const float* __restrict__ bk,
    const float* __restrict__ bv,
    float* __restrict__ Qo, float* __restrict__ Ko, float* __restrict__ Vo,
    int reps)
{
    const int z = blockIdx.z;
    const float* bm = (z == 0) ? bq : (z == 1) ? bk : bv;
    float* Om       = (z == 0) ? Qo : (z == 1) ? Ko : Vo;
    const unsigned short* Whz = Wh + (size_t)z * 65536;
    const unsigned short* Wlz = Wl + (size_t)z * 65536;

    const int wave = threadIdx.x >> 6;
    const int lane = threadIdx.x & 63;
    const int rsel = lane & 15;
    const int koff = (lane >> 4) * 8;

    const int m0 = blockIdx.x * 32;
    const int nb = blockIdx.y * 128 + wave * 32;

    const unsigned short* pa0h = Ah + (size_t)(m0 + rsel) * 256 + koff;
    const unsigned short* pa0l = Al + (size_t)(m0 + rsel) * 256 + koff;
    const unsigned short* pa1h = pa0h + 16 * 256;
    const unsigned short* pa1l = pa0l + 16 * 256;
    const unsigned short* pw0h = Whz + (size_t)(nb + rsel) * 256 + koff;
    const unsigned short* pw0l = Wlz + (size_t)(nb + rsel) * 256 + koff;
    const unsigned short* pw1h = pw0h + 16 * 256;
    const unsigned short* pw1l = pw0l + 16 * 256;

    for (int rep = 0; rep < reps; ++rep) {
        f32x4 acc[2][2];
#pragma unroll
        for (int mt = 0; mt < 2; ++mt)
#pragma unroll
            for (int nt = 0; nt < 2; ++nt)
                acc[mt][nt] = (f32x4){0.f, 0.f, 0.f, 0.f};

#pragma unroll
        for (int k0 = 0; k0 < 256; k0 += 32) {
            bf16x8 ah[2], al[2], bh[2], bl[2];
            ah[0] = *(const bf16x8*)(pa0h + k0);
            al[0] = *(const bf16x8*)(pa0l + k0);
            ah[1] = *(const bf16x8*)(pa1h + k0);
            al[1] = *(const bf16x8*)(pa1l + k0);
            bh[0] = *(const bf16x8*)(pw0h + k0);
            bl[0] = *(const bf16x8*)(pw0l + k0);
            bh[1] = *(const bf16x8*)(pw1h + k0);
            bl[1] = *(const bf16x8*)(pw1l + k0);
#pragma unroll
            for (int mt = 0; mt < 2; ++mt)
#pragma unroll
                for (int nt = 0; nt < 2; ++nt) {
                    acc[mt][nt] = __builtin_amdgcn_mfma_f32_16x16x32_bf16(
                        ah[mt], bh[nt], acc[mt][nt], 0, 0, 0);
                    acc[mt][nt] = __builtin_amdgcn_mfma_f32_16x16x32_bf16(
                        ah[mt], bl[nt], acc[mt][nt], 0, 0, 0);
                    acc[mt][nt] = __builtin_amdgcn_mfma_f32_16x16x32_bf16(
                        al[mt], bh[nt], acc[mt][nt], 0, 0, 0);
                }
        }

#pragma unroll
        for (int mt = 0; mt < 2; ++mt) {
            const int mrow = m0 + mt * 16 + (lane >> 4) * 4;
#pragma unroll
            for (int nt = 0; nt < 2; ++nt) {
                const int n = nb + nt * 16 + rsel;
                const float bias = bm[n];
#pragma unroll
                for (int r = 0; r < 4; ++r)
                    Om[(size_t)(mrow + r) * 256 + n] = acc[mt][nt][r] + bias;
            }
        }
    }
}

// ===========================================================================
// Kernel 2: windowed softmax — R7's aft_stage3 with a `reps` outer loop
// (MEASUREMENT: reps=4, idempotent rewrites; divide dispatch dur by 4).
// ===========================================================================
#define SPS 36

__global__ __launch_bounds__(256, 4) void aft_stage3(
    const float* __restrict__ Q, const float* __restrict__ K,
    const float* __restrict__ V, const float* __restrict__ pb,
    float* __restrict__ out, int reps)
{
    __shared__ float Pw[2 * S_ + 1][SPS];

    const int tid = threadIdx.x;
    const int i0 = blockIdx.x * 32;
    const int b  = blockIdx.y;
    const int c0 = blockIdx.z * 32;

    for (int idx = tid; idx < 65 * 8; idx += 256) {
        const int r = idx >> 3;
        const int q = (idx & 7) * 4;
        *(float4*)&Pw[r][q] = *(const float4*)(pb + (size_t)r * E_ + c0 + q);
    }
    __syncthreads();

    const int c4 = (tid & 7) * 4;
    const int ro = tid >> 3;
    const int i  = i0 + ro;

    const float4 qv = *(const float4*)(Q + ((size_t)b * L_ + i) * E_ + c0 + c4);
    const float q2x = qv.x * LOG2E, q2y = qv.y * LOG2E;
    const float q2z = qv.z * LOG2E, q2w = qv.w * LOG2E;

    const float* kp = K + ((size_t)b * L_ + (i - S_)) * E_ + c0 + c4;
    const float* vp = V + ((size_t)b * L_ + (i - S_)) * E_ + c0 + c4;

    const bool interior = (blockIdx.x >= 1) && (blockIdx.x <= 30);

    for (int rep = 0; rep < reps; ++rep) {
        float den0 = 0.f, den1 = 0.f, den2 = 0.f, den3 = 0.f;
        float num0 = 0.f, num1 = 0.f, num2 = 0.f, num3 = 0.f;

        if (interior) {
            {   // w = 0: edge tap, e = 1
                const float4 v = *(const float4*)vp;
                den0 += 1.f; den1 += 1.f; den2 += 1.f; den3 += 1.f;
                num0 += v.x; num1 += v.y; num2 += v.z; num3 += v.w;
            }
#pragma unroll 7
            for (int w = 1; w <= 63; ++w) {
                const float4 kk = *(const float4*)(kp + (size_t)w * E_);
                const float4 vv = *(const float4*)(vp + (size_t)w * E_);
                const float4 pp = *(const float4*)&Pw[w][c4];
                const float e0 = __builtin_amdgcn_exp2f(q2x * (kk.x + pp.x));
                const float e1 = __builtin_amdgcn_exp2f(q2y * (kk.y + pp.y));
                const float e2 = __builtin_amdgcn_exp2f(q2z * (kk.z + pp.z));
                const float e3 = __builtin_amdgcn_exp2f(q2w * (kk.w + pp.w));
                den0 += e0; den1 += e1; den2 += e2; den3 += e3;
                num0 += e0 * vv.x; num1 += e1 * vv.y;
                num2 += e2 * vv.z; num3 += e3 * vv.w;
            }
            {   // w = 64: edge tap, e = 1
                const float4 v = *(const float4*)(vp + (size_t)64 * E_);
                den0 += 1.f; den1 += 1.f; den2 += 1.f; den3 += 1.f;
                num0 += v.x; num1 += v.y; num2 += v.z; num3 += v.w;
            }
        } else {
            const float* KbB = K + (size_t)b * L_ * E_ + c0 + c4;
            const float* VbB = V + (size_t)b * L_ * E_ + c0 + c4;
            for (int w = 0; w <= 64; ++w) {
                const int j = i - S_ + w;
                const bool valid = (unsigned)j < (unsigned)L_;
                const int jc = j < 0 ? 0 : (j > L_ - 1 ? L_ - 1 : j);
                const float4 kk = *(const float4*)(KbB + (size_t)jc * E_);
                const float4 vv = *(const float4*)(VbB + (size_t)jc * E_);
                const float4 pp = *(const float4*)&Pw[w][c4];
                const bool edge = (w == 0) || (w == 64);
                const float lx = edge ? 0.f : q2x * (kk.x + pp.x);
                const float ly = edge ? 0.f : q2y * (kk.y + pp.y);
                const float lz = edge ? 0.f : q2z * (kk.z + pp.z);
                const float lw = edge ? 0.f : q2w * (kk.w + pp.w);
                const float e0 = valid ? __builtin_amdgcn_exp2f(lx) : 0.f;
                const float e1 = valid ? __builtin_amdgcn_exp2f(ly) : 0.f;
                const float e2 = valid ? __builtin_amdgcn_exp2f(lz) : 0.f;
                const float e3 = valid ? __builtin_amdgcn_exp2f(lw) : 0.f;
                den0 += e0; den1 += e1; den2 += e2; den3 += e3;
                num0 += e0 * vv.x; num1 += e1 * vv.y;
                num2 += e2 * vv.z; num3 += e3 * vv.w;
            }
        }

        const float s0 = 1.f / (1.f + __builtin_amdgcn_exp2f(-q2x));
        const float s1 = 1.f / (1.f + __builtin_amdgcn_exp2f(-q2y));
        const float s2 = 1.f / (1.f + __builtin_amdgcn_exp2f(-q2z));
        const float s3 = 1.f / (1.f + __builtin_amdgcn_exp2f(-q2w));
        float4 o;
        o.x = s0 * s0 * num0 / den0;
        o.y = s1 * s1 * num1 / den1;
        o.z = s2 * s2 * num2 / den2;
        o.w = s3 * s3 * num3 / den3;
        *(float4*)(out + ((size_t)b * L_ + i) * E_ + c0 + c4) = o;
    }
}

// ===========================================================================
// PATH B (ws too small; fallback only): fused fp32 in-register split (r3).
// ===========================================================================
#define TI 32
#define CG 64
#define RK 96
#define LDP 68

__global__ __launch_bounds__(256) void aft_fused(
    const float* __restrict__ q,
    const float* __restrict__ Wq, const float* __restrict__ bq,
    const float* __restrict__ Wk, const float* __restrict__ bk,
    const float* __restrict__ Wv, const float* __restrict__ bv,
    const float* __restrict__ pb,
    float* __restrict__ out)
{
    __shared__ float Kl[RK][LDP];
    __shared__ float Vl[RK][LDP];
    __shared__ float Ql[TI][LDP];

    const int i0 = blockIdx.x * TI;
    const int b  = blockIdx.y;
    const int c0 = blockIdx.z * CG;

    const int wave = threadIdx.x >> 6;
    const int lane = threadIdx.x & 63;
    const int rsel = lane & 15;
    const int koff = (lane >> 4) * 8;

    const float* qb = q + (size_t)b * L_ * E_;

    for (int job = wave; job < 56; job += 4) {
        int p, rt, ct;
        if (job < 24)      { p = 0; rt = job >> 2;        ct = job & 3; }
        else if (job < 48) { p = 1; rt = (job - 24) >> 2; ct = (job - 24) & 3; }
        else               { p = 2; rt = (job - 48) >> 2; ct = (job - 48) & 3; }

        int jrow = (p == 2) ? (i0 + rt * 16 + rsel)
                            : (i0 - S_ + rt * 16 + rsel);
        int jc = jrow < 0 ? 0 : (jrow > L_ - 1 ? L_ - 1 : jrow);
        const float* pa = qb + (size_t)jc * E_ + koff;

        const float* Wm = (p == 0) ? Wk : (p == 1) ? Wv : Wq;
        const float* bm = (p == 0) ? bk : (p == 1) ? bv : bq;
        const int n = c0 + ct * 16 + rsel;
        const float* pw = Wm + (size_t)n * E_ + koff;

        f32x4 acc = {0.f, 0.f, 0.f, 0.f};
#pragma unroll
        for (int k0 = 0; k0 < 256; k0 += 32) {
            bf16x8 ah, al, bh, bl;
            load8split(pa + k0, ah, al);
            load8split(pw + k0, bh, bl);
            acc = __builtin_amdgcn_mfma_f32_16x16x32_bf16(ah, bh, acc, 0, 0, 0);
            acc = __builtin_amdgcn_mfma_f32_16x16x32_bf16(ah, bl, acc, 0, 0, 0);
            acc = __builtin_amdgcn_mfma_f32_16x16x32_bf16(al, bh, acc, 0, 0, 0);
        }

        const float bias = bm[n];
        const int row0 = rt * 16 + (lane >> 4) * 4;
        const int colc = ct * 16 + rsel;
        float* dst = (p == 0) ? &Kl[0][0] : (p == 1) ? &Vl[0][0] : &Ql[0][0];
#pragma unroll
        for (int r = 0; r < 4; ++r)
            dst[(size_t)(row0 + r) * LDP + colc] = acc[r] + bias;
    }
    __syncthreads();

    const int cq  = threadIdx.x & 15;
    const int is0 = threadIdx.x >> 4;
    const int cL  = cq * 4;
    const int cG  = c0 + cL;
    const float* pbc = pb + cG;

    for (int rr = is0; rr < TI; rr += 16) {
        const int i = i0 + rr;
        const float4 qv = *(const float4*)&Ql[rr][cL];

        float den0 = 0.f, den1 = 0.f, den2 = 0.f, den3 = 0.f;
        float num0 = 0.f, num1 = 0.f, num2 = 0.f, num3 = 0.f;

        const int jlo = (i - S_ < 0) ? 0 : (i - S_);
        const int jhi = (i + S_ > L_ - 1) ? (L_ - 1) : (i + S_);

        for (int j = jlo; j <= jhi; ++j) {
            const int r = j - (i0 - S_);
            const int w = j - i + S_;
            const float4 vv = *(const float4*)&Vl[r][cL];

            float kx = 0.f, ky = 0.f, kz = 0.f, kw = 0.f;
            if (w != 0 && w != 2 * S_) {
                const float4 kk = *(const float4*)&Kl[r][cL];
                const float4 pp = *(const float4*)(pbc + (size_t)w * E_);
                kx = kk.x + pp.x;
                ky = kk.y + pp.y;
                kz = kk.z + pp.z;
                kw = kk.w + pp.w;
            }
            const float e0 = __expf(qv.x * kx);
            const float e1 = __expf(qv.y * ky);
            const float e2 = __expf(qv.z * kz);
            const float e3 = __expf(qv.w * kw);
            den0 += e0; den1 += e1; den2 += e2; den3 += e3;
            num0 += e0 * vv.x; num1 += e1 * vv.y;
            num2 += e2 * vv.z; num3 += e3 * vv.w;
        }

        const float s0 = 1.f / (1.f + __expf(-qv.x));
        const float s1 = 1.f / (1.f + __expf(-qv.y));
        const float s2 = 1.f / (1.f + __expf(-qv.z));
        const float s3 = 1.f / (1.f + __expf(-qv.w));

        float4 o;
        o.x = s0 * s0 * num0 / den0;
        o.y = s1 * s1 * num1 / den1;
        o.z = s2 * s2 * num2 / den2;
        o.w = s3 * s3 * num3 / den3;
        *(float4*)(out + ((size_t)b * L_ + i) * E_ + cG) = o;
    }
}

extern "C" void kernel_launch(void* const* d_in, const int* in_sizes, int n_in,
                              void* d_out, int out_size, void* d_ws, size_t ws_size,
                              hipStream_t stream) {
    const float* q  = (const float*)d_in[0];
    const float* Wq = (const float*)d_in[1];
    const float* bq = (const float*)d_in[2];
    const float* Wk = (const float*)d_in[3];
    const float* bk = (const float*)d_in[4];
    const float* Wv = (const float*)d_in[5];
    const float* bv = (const float*)d_in[6];
    const float* pb = (const float*)d_in[7];

    const size_t needA = (size_t)3 * 1048576 * 4
                       + ((size_t)2 * 1048576 + (size_t)2 * 196608) * 2;

    if (ws_size >= needA) {
        float* Qf = (float*)d_ws;
        float* Kf = Qf + 1048576;
        float* Vf = Kf + 1048576;
        unsigned short* Ah = (unsigned short*)(Vf + 1048576);
        unsigned short* Al = Ah + 1048576;
        unsigned short* Wh = Al + 1048576;
        unsigned short* Wl = Wh + 196608;

        presplit<<<dim3(608), 256, 0, stream>>>(q, Wq, Wk, Wv, Ah, Al, Wh, Wl);
        // MEASUREMENT ROUND: reps=4 on both kernels (idempotent). True
        // per-kernel dur = dispatch dur / 4; dur_R8 - dur_R7 = 3*(G+S).
        qkv_gemm4<<<dim3(128, 2, 3), 256, 0, stream>>>(Ah, Al, Wh, Wl,
                                                       bq, bk, bv, Qf, Kf, Vf, 4);
        aft_stage3<<<dim3(32, 4, 8), 256, 0, stream>>>(Qf, Kf, Vf, pb,
                                                       (float*)d_out, 4);
    } else {
        aft_fused<<<dim3(L_ / TI, B_, E_ / CG), 256, 0, stream>>>(
            q, Wq, bq, Wk, bk, Wv, bv, pb, (float*)d_out);
    }
}

// Round 9
// 140.218 us; speedup vs baseline: 1.3984x; 1.3984x over previous
//
#include <hip/hip_runtime.h>
#include <hip/hip_bf16.h>

#define B_ 4
#define L_ 1024
#define E_ 256
#define S_ 32
#define LOG2E 1.4426950408889634f

typedef __bf16 bf16x8 __attribute__((ext_vector_type(8)));
typedef float f32x4 __attribute__((ext_vector_type(4)));

__device__ __forceinline__ __bf16 bf_from_bits(unsigned short u) {
    __bf16 b;
    __builtin_memcpy(&b, &u, 2);
    return b;
}

__device__ __forceinline__ void split1(float x, unsigned short& h, unsigned short& l) {
    const unsigned u  = __float_as_uint(x);
    const unsigned hb = u & 0xFFFF0000u;
    h = (unsigned short)(hb >> 16);
    __bf16 lo = (__bf16)(x - __uint_as_float(hb));
    unsigned short lu;
    __builtin_memcpy(&lu, &lo, 2);
    l = lu;
}

// Path-B fallback only.
__device__ __forceinline__ void load8split(const float* __restrict__ p,
                                           bf16x8& h, bf16x8& l) {
    const float4 x0 = *(const float4*)p;
    const float4 x1 = *(const float4*)(p + 4);
    const float xs[8] = {x0.x, x0.y, x0.z, x0.w, x1.x, x1.y, x1.z, x1.w};
#pragma unroll
    for (int j = 0; j < 8; ++j) {
        const unsigned hb = __float_as_uint(xs[j]) & 0xFFFF0000u;
        h[j] = bf_from_bits((unsigned short)(__float_as_uint(xs[j]) >> 16));
        l[j] = (__bf16)(xs[j] - __uint_as_float(hb));
    }
}

// normal tap: den += e, num += e*v, e = exp2(q2*(k+p)) per channel
__device__ __forceinline__ void tap_n(const float4& q2, const float4& k,
                                      const float4& p, const float4& v,
                                      float4& den, float4& num) {
    const float e0 = __builtin_amdgcn_exp2f(q2.x * (k.x + p.x));
    const float e1 = __builtin_amdgcn_exp2f(q2.y * (k.y + p.y));
    const float e2 = __builtin_amdgcn_exp2f(q2.z * (k.z + p.z));
    const float e3 = __builtin_amdgcn_exp2f(q2.w * (k.w + p.w));
    den.x += e0; den.y += e1; den.z += e2; den.w += e3;
    num.x += e0 * v.x; num.y += e1 * v.y;
    num.z += e2 * v.z; num.w += e3 * v.w;
}

// edge tap (strict mask -> logit 0 -> e = 1)
__device__ __forceinline__ void tap_e(const float4& v, float4& den, float4& num) {
    den.x += 1.f; den.y += 1.f; den.z += 1.f; den.w += 1.f;
    num.x += v.x; num.y += v.y; num.z += v.z; num.w += v.w;
}

// ===========================================================================
// Kernel 0: presplit (unchanged).
// ===========================================================================
__global__ __launch_bounds__(256) void presplit(
    const float* __restrict__ A,
    const float* __restrict__ Wq, const float* __restrict__ Wk,
    const float* __restrict__ Wv,
    unsigned short* __restrict__ Ah, unsigned short* __restrict__ Al,
    unsigned short* __restrict__ Wh, unsigned short* __restrict__ Wl)
{
    const int e8 = (blockIdx.x * 256 + threadIdx.x) * 8;
    const float* src;
    unsigned short* dh;
    unsigned short* dl;
    if (e8 < 1048576) {
        src = A + e8; dh = Ah + e8; dl = Al + e8;
    } else {
        const int r = e8 - 1048576;
        const int m = r >> 16;          // 0=Wq 1=Wk 2=Wv
        const int o = r & 65535;
        src = (m == 0 ? Wq : m == 1 ? Wk : Wv) + o;
        dh = Wh + r; dl = Wl + r;
    }
    const float4 x0 = *(const float4*)src;
    const float4 x1 = *(const float4*)(src + 4);
    const float xs[8] = {x0.x, x0.y, x0.z, x0.w, x1.x, x1.y, x1.z, x1.w};
    unsigned short hs[8], ls[8];
#pragma unroll
    for (int j = 0; j < 8; ++j) split1(xs[j], hs[j], ls[j]);
    *(ushort4*)(dh)     = make_ushort4(hs[0], hs[1], hs[2], hs[3]);
    *(ushort4*)(dh + 4) = make_ushort4(hs[4], hs[5], hs[6], hs[7]);
    *(ushort4*)(dl)     = make_ushort4(ls[0], ls[1], ls[2], ls[3]);
    *(ushort4*)(dl + 4) = make_ushort4(ls[4], ls[5], ls[6], ls[7]);
}

// ===========================================================================
// Kernel 1: Q/K/V projection GEMM (R7 structure; reps kept for future probes,
// launched with reps=1). Measured R8: G small (<~8 us total with presplit).
// ===========================================================================
__global__ __launch_bounds__(256) void qkv_gemm4(
    const unsigned short* __restrict__ Ah, const unsigned short* __restrict__ Al,
    const unsigned short* __restrict__ Wh, const unsigned short* __restrict__ Wl,
    const float* __restrict__ bq, const float* __restrict__ bk,
    const float* __restrict__ bv,
    float* __restrict__ Qo, float* __restrict__ Ko, float* __restrict__ Vo,
    int reps)
{
    const int z = blockIdx.z;
    const float* bm = (z == 0) ? bq : (z == 1) ? bk : bv;
    float* Om       = (z == 0) ? Qo : (z == 1) ? Ko : Vo;
    const unsigned short* Whz = Wh + (size_t)z * 65536;
    const unsigned short* Wlz = Wl + (size_t)z * 65536;

    const int wave = threadIdx.x >> 6;
    const int lane = threadIdx.x & 63;
    const int rsel = lane & 15;
    const int koff = (lane >> 4) * 8;

    const int m0 = blockIdx.x * 32;
    const int nb = blockIdx.y * 128 + wave * 32;

    const unsigned short* pa0h = Ah + (size_t)(m0 + rsel) * 256 + koff;
    const unsigned short* pa0l = Al + (size_t)(m0 + rsel) * 256 + koff;
    const unsigned short* pa1h = pa0h + 16 * 256;
    const unsigned short* pa1l = pa0l + 16 * 256;
    const unsigned short* pw0h = Whz + (size_t)(nb + rsel) * 256 + koff;
    const unsigned short* pw0l = Wlz + (size_t)(nb + rsel) * 256 + koff;
    const unsigned short* pw1h = pw0h + 16 * 256;
    const unsigned short* pw1l = pw0l + 16 * 256;

    for (int rep = 0; rep < reps; ++rep) {
        f32x4 acc[2][2];
#pragma unroll
        for (int mt = 0; mt < 2; ++mt)
#pragma unroll
            for (int nt = 0; nt < 2; ++nt)
                acc[mt][nt] = (f32x4){0.f, 0.f, 0.f, 0.f};

#pragma unroll
        for (int k0 = 0; k0 < 256; k0 += 32) {
            bf16x8 ah[2], al[2], bh[2], bl[2];
            ah[0] = *(const bf16x8*)(pa0h + k0);
            al[0] = *(const bf16x8*)(pa0l + k0);
            ah[1] = *(const bf16x8*)(pa1h + k0);
            al[1] = *(const bf16x8*)(pa1l + k0);
            bh[0] = *(const bf16x8*)(pw0h + k0);
            bl[0] = *(const bf16x8*)(pw0l + k0);
            bh[1] = *(const bf16x8*)(pw1h + k0);
            bl[1] = *(const bf16x8*)(pw1l + k0);
#pragma unroll
            for (int mt = 0; mt < 2; ++mt)
#pragma unroll
                for (int nt = 0; nt < 2; ++nt) {
                    acc[mt][nt] = __builtin_amdgcn_mfma_f32_16x16x32_bf16(
                        ah[mt], bh[nt], acc[mt][nt], 0, 0, 0);
                    acc[mt][nt] = __builtin_amdgcn_mfma_f32_16x16x32_bf16(
                        ah[mt], bl[nt], acc[mt][nt], 0, 0, 0);
                    acc[mt][nt] = __builtin_amdgcn_mfma_f32_16x16x32_bf16(
                        al[mt], bh[nt], acc[mt][nt], 0, 0, 0);
                }
        }

#pragma unroll
        for (int mt = 0; mt < 2; ++mt) {
            const int mrow = m0 + mt * 16 + (lane >> 4) * 4;
#pragma unroll
            for (int nt = 0; nt < 2; ++nt) {
                const int n = nb + nt * 16 + rsel;
                const float bias = bm[n];
#pragma unroll
                for (int r = 0; r < 4; ++r)
                    Om[(size_t)(mrow + r) * 256 + n] = acc[mt][nt][r] + bias;
            }
        }
    }
}

// ===========================================================================
// Kernel 2: windowed softmax, 4-ROWS-PER-THREAD (R8 showed stage3 was
// L2-BW-bound: 528 MB window re-reads ~ 15us + latency = 24.7us measured).
// Thread = (channel-quad, 4 consecutive rows): one K/V float4 load per tap
// serves 4 rows (4x traffic cut); per-row pos_bias via 4-deep register
// carry (row r at tap t uses P loaded r taps ago). 8 boundary taps with
// compile-time t peel the w=0/64 edges (strict mask -> e=1). Sequence-edge
// rows (i<32 | i>988) take a guarded path; block = 128 rows so the guard
// is wave-uniform (wave 0 of x=0, wave 3 of x=7).
// Block 256 = 8 ch-quads x 32 row-groups; grid (8, 4, 8) = 256 blocks.
// ===========================================================================
__global__ __launch_bounds__(256) void aft_stage4(
    const float* __restrict__ Q, const float* __restrict__ K,
    const float* __restrict__ V, const float* __restrict__ pb,
    float* __restrict__ out)
{
    __shared__ float Pw[2 * S_ + 1][36];

    const int tid = threadIdx.x;
    const int b  = blockIdx.y;
    const int c0 = blockIdx.z * 32;

    // stage pos_bias slice: 65 rows x 8 quads (broadcast reads later)
    for (int idx = tid; idx < 65 * 8; idx += 256) {
        const int r = idx >> 3;
        const int q = (idx & 7) * 4;
        *(float4*)&Pw[r][q] = *(const float4*)(pb + (size_t)r * E_ + c0 + q);
    }
    __syncthreads();

    const int c4 = (tid & 7) * 4;          // channel quad
    const int g  = tid >> 3;               // row-group 0..31
    const int i  = blockIdx.x * 128 + g * 4;

    const float* Qp = Q + ((size_t)b * L_ + i) * E_ + c0 + c4;
    const float* Kp = K + ((size_t)b * L_ + i) * E_ + c0 + c4;
    const float* Vp = V + ((size_t)b * L_ + i) * E_ + c0 + c4;

    float4 q2[4], den[4], num[4];
#pragma unroll
    for (int r = 0; r < 4; ++r) {
        const float4 qv = *(const float4*)(Qp + (size_t)r * E_);
        q2[r] = make_float4(qv.x * LOG2E, qv.y * LOG2E, qv.z * LOG2E, qv.w * LOG2E);
        den[r] = make_float4(0.f, 0.f, 0.f, 0.f);
        num[r] = make_float4(0.f, 0.f, 0.f, 0.f);
    }

    const bool guarded = (i < 32) || (i > L_ - 36);

    if (!guarded) {
        // ---- main: t = -28..31, all 4 rows normal (w_r = t+32-r in [1,63]) ----
        float4 ph1 = *(const float4*)&Pw[3][c4];   // row1 history P[t+31]
        float4 ph2 = *(const float4*)&Pw[2][c4];
        float4 ph3 = *(const float4*)&Pw[1][c4];
#pragma unroll 4
        for (int t = -28; t <= 31; ++t) {
            const float4 k = *(const float4*)(Kp + (ptrdiff_t)t * E_);
            const float4 v = *(const float4*)(Vp + (ptrdiff_t)t * E_);
            const float4 p0 = *(const float4*)&Pw[t + 32][c4];
            tap_n(q2[0], k, p0,  v, den[0], num[0]);
            tap_n(q2[1], k, ph1, v, den[1], num[1]);
            tap_n(q2[2], k, ph2, v, den[2], num[2]);
            tap_n(q2[3], k, ph3, v, den[3], num[3]);
            ph3 = ph2; ph2 = ph1; ph1 = p0;
        }
        // ---- 8 boundary taps (compile-time t; w_r = t+32-r) ----
        const int TB[8] = {-32, -31, -30, -29, 32, 33, 34, 35};
#pragma unroll
        for (int s = 0; s < 8; ++s) {
            const int t = TB[s];
            const float4 k = *(const float4*)(Kp + (ptrdiff_t)t * E_);
            const float4 v = *(const float4*)(Vp + (ptrdiff_t)t * E_);
#pragma unroll
            for (int r = 0; r < 4; ++r) {
                const int w = t + 32 - r;
                if (w == 0 || w == 64)
                    tap_e(v, den[r], num[r]);
                else if (w >= 1 && w <= 63)
                    tap_n(q2[r], k, *(const float4*)&Pw[w][c4], v, den[r], num[r]);
            }
        }
    } else {
        // ---- guarded path: full predicates, clamped j ----
        for (int t = -32; t <= 35; ++t) {
            const int j = i + t;
            const bool jv = (unsigned)j < (unsigned)L_;
            const int jc = j < 0 ? 0 : (j > L_ - 1 ? L_ - 1 : j);
            const float4 k = *(const float4*)(K + ((size_t)b * L_ + jc) * E_ + c0 + c4);
            const float4 v = *(const float4*)(V + ((size_t)b * L_ + jc) * E_ + c0 + c4);
#pragma unroll
            for (int r = 0; r < 4; ++r) {
                const int w = t + 32 - r;
                if (jv && (w == 0 || w == 64))
                    tap_e(v, den[r], num[r]);
                else if (jv && w >= 1 && w <= 63)
                    tap_n(q2[r], k, *(const float4*)&Pw[w][c4], v, den[r], num[r]);
            }
        }
    }

    // ---- epilogue: sigmoid^2 * ctx ----
#pragma unroll
    for (int r = 0; r < 4; ++r) {
        const float s0 = 1.f / (1.f + __builtin_amdgcn_exp2f(-q2[r].x));
        const float s1 = 1.f / (1.f + __builtin_amdgcn_exp2f(-q2[r].y));
        const float s2 = 1.f / (1.f + __builtin_amdgcn_exp2f(-q2[r].z));
        const float s3 = 1.f / (1.f + __builtin_amdgcn_exp2f(-q2[r].w));
        float4 o;
        o.x = s0 * s0 * num[r].x / den[r].x;
        o.y = s1 * s1 * num[r].y / den[r].y;
        o.z = s2 * s2 * num[r].z / den[r].z;
        o.w = s3 * s3 * num[r].w / den[r].w;
        *(float4*)(out + ((size_t)b * L_ + i + r) * E_ + c0 + c4) = o;
    }
}

// ===========================================================================
// PATH B (ws too small; fallback only): fused fp32 in-register split (r3).
// ===========================================================================
#define TI 32
#define CG 64
#define RK 96
#define LDP 68

__global__ __launch_bounds__(256) void aft_fused(
    const float* __restrict__ q,
    const float* __restrict__ Wq, const float* __restrict__ bq,
    const float* __restrict__ Wk, const float* __restrict__ bk,
    const float* __restrict__ Wv, const float* __restrict__ bv,
    const float* __restrict__ pb,
    float* __restrict__ out)
{
    __shared__ float Kl[RK][LDP];
    __shared__ float Vl[RK][LDP];
    __shared__ float Ql[TI][LDP];

    const int i0 = blockIdx.x * TI;
    const int b  = blockIdx.y;
    const int c0 = blockIdx.z * CG;

    const int wave = threadIdx.x >> 6;
    const int lane = threadIdx.x & 63;
    const int rsel = lane & 15;
    const int koff = (lane >> 4) * 8;

    const float* qb = q + (size_t)b * L_ * E_;

    for (int job = wave; job < 56; job += 4) {
        int p, rt, ct;
        if (job < 24)      { p = 0; rt = job >> 2;        ct = job & 3; }
        else if (job < 48) { p = 1; rt = (job - 24) >> 2; ct = (job - 24) & 3; }
        else               { p = 2; rt = (job - 48) >> 2; ct = (job - 48) & 3; }

        int jrow = (p == 2) ? (i0 + rt * 16 + rsel)
                            : (i0 - S_ + rt * 16 + rsel);
        int jc = jrow < 0 ? 0 : (jrow > L_ - 1 ? L_ - 1 : jrow);
        const float* pa = qb + (size_t)jc * E_ + koff;

        const float* Wm = (p == 0) ? Wk : (p == 1) ? Wv : Wq;
        const float* bm = (p == 0) ? bk : (p == 1) ? bv : bq;
        const int n = c0 + ct * 16 + rsel;
        const float* pw = Wm + (size_t)n * E_ + koff;

        f32x4 acc = {0.f, 0.f, 0.f, 0.f};
#pragma unroll
        for (int k0 = 0; k0 < 256; k0 += 32) {
            bf16x8 ah, al, bh, bl;
            load8split(pa + k0, ah, al);
            load8split(pw + k0, bh, bl);
            acc = __builtin_amdgcn_mfma_f32_16x16x32_bf16(ah, bh, acc, 0, 0, 0);
            acc = __builtin_amdgcn_mfma_f32_16x16x32_bf16(ah, bl, acc, 0, 0, 0);
            acc = __builtin_amdgcn_mfma_f32_16x16x32_bf16(al, bh, acc, 0, 0, 0);
        }

        const float bias = bm[n];
        const int row0 = rt * 16 + (lane >> 4) * 4;
        const int colc = ct * 16 + rsel;
        float* dst = (p == 0) ? &Kl[0][0] : (p == 1) ? &Vl[0][0] : &Ql[0][0];
#pragma unroll
        for (int r = 0; r < 4; ++r)
            dst[(size_t)(row0 + r) * LDP + colc] = acc[r] + bias;
    }
    __syncthreads();

    const int cq  = threadIdx.x & 15;
    const int is0 = threadIdx.x >> 4;
    const int cL  = cq * 4;
    const int cG  = c0 + cL;
    const float* pbc = pb + cG;

    for (int rr = is0; rr < TI; rr += 16) {
        const int i = i0 + rr;
        const float4 qv = *(const float4*)&Ql[rr][cL];

        float den0 = 0.f, den1 = 0.f, den2 = 0.f, den3 = 0.f;
        float num0 = 0.f, num1 = 0.f, num2 = 0.f, num3 = 0.f;

        const int jlo = (i - S_ < 0) ? 0 : (i - S_);
        const int jhi = (i + S_ > L_ - 1) ? (L_ - 1) : (i + S_);

        for (int j = jlo; j <= jhi; ++j) {
            const int r = j - (i0 - S_);
            const int w = j - i + S_;
            const float4 vv = *(const float4*)&Vl[r][cL];

            float kx = 0.f, ky = 0.f, kz = 0.f, kw = 0.f;
            if (w != 0 && w != 2 * S_) {
                const float4 kk = *(const float4*)&Kl[r][cL];
                const float4 pp = *(const float4*)(pbc + (size_t)w * E_);
                kx = kk.x + pp.x;
                ky = kk.y + pp.y;
                kz = kk.z + pp.z;
                kw = kk.w + pp.w;
            }
            const float e0 = __expf(qv.x * kx);
            const float e1 = __expf(qv.y * ky);
            const float e2 = __expf(qv.z * kz);
            const float e3 = __expf(qv.w * kw);
            den0 += e0; den1 += e1; den2 += e2; den3 += e3;
            num0 += e0 * vv.x; num1 += e1 * vv.y;
            num2 += e2 * vv.z; num3 += e3 * vv.w;
        }

        const float s0 = 1.f / (1.f + __expf(-qv.x));
        const float s1 = 1.f / (1.f + __expf(-qv.y));
        const float s2 = 1.f / (1.f + __expf(-qv.z));
        const float s3 = 1.f / (1.f + __expf(-qv.w));

        float4 o;
        o.x = s0 * s0 * num0 / den0;
        o.y = s1 * s1 * num1 / den1;
        o.z = s2 * s2 * num2 / den2;
        o.w = s3 * s3 * num3 / den3;
        *(float4*)(out + ((size_t)b * L_ + i) * E_ + cG) = o;
    }
}

extern "C" void kernel_launch(void* const* d_in, const int* in_sizes, int n_in,
                              void* d_out, int out_size, void* d_ws, size_t ws_size,
                              hipStream_t stream) {
    const float* q  = (const float*)d_in[0];
    const float* Wq = (const float*)d_in[1];
    const float* bq = (const float*)d_in[2];
    const float* Wk = (const float*)d_in[3];
    const float* bk = (const float*)d_in[4];
    const float* Wv = (const float*)d_in[5];
    const float* bv = (const float*)d_in[6];
    const float* pb = (const float*)d_in[7];

    const size_t needA = (size_t)3 * 1048576 * 4
                       + ((size_t)2 * 1048576 + (size_t)2 * 196608) * 2;

    if (ws_size >= needA) {
        float* Qf = (float*)d_ws;
        float* Kf = Qf + 1048576;
        float* Vf = Kf + 1048576;
        unsigned short* Ah = (unsigned short*)(Vf + 1048576);
        unsigned short* Al = Ah + 1048576;
        unsigned short* Wh = Al + 1048576;
        unsigned short* Wl = Wh + 196608;

        presplit<<<dim3(608), 256, 0, stream>>>(q, Wq, Wk, Wv, Ah, Al, Wh, Wl);
        qkv_gemm4<<<dim3(128, 2, 3), 256, 0, stream>>>(Ah, Al, Wh, Wl,
                                                       bq, bk, bv, Qf, Kf, Vf, 1);
        aft_stage4<<<dim3(8, 4, 8), 256, 0, stream>>>(Qf, Kf, Vf, pb,
                                                      (float*)d_out);
    } else {
        aft_fused<<<dim3(L_ / TI, B_, E_ / CG), 256, 0, stream>>>(
            q, Wq, bq, Wk, bk, Wv, bv, pb, (float*)d_out);
    }
}